// Round 11
// baseline (109.077 us; speedup 1.0000x reference)
//
#include <hip/hip_runtime.h>
#include <hip/hip_bf16.h>

typedef unsigned short u16;
using frag_ab = __attribute__((ext_vector_type(8))) short;
using f32x4   = __attribute__((ext_vector_type(4))) float;
using u16x4   = __attribute__((ext_vector_type(4))) unsigned short;
using u16x8   = __attribute__((ext_vector_type(8))) unsigned short;

#define N_CTX   2048
#define NBATCH  2
#define CDIM    1024
#define NH      16
#define HD      64

__device__ __forceinline__ u16 f2b(float f) {
  __hip_bfloat16 h = __float2bfloat16(f);
  return __builtin_bit_cast(u16, h);
}

__device__ __forceinline__ f32x4 mfma16(frag_ab a, frag_ab b, f32x4 c) {
  return __builtin_amdgcn_mfma_f32_16x16x32_bf16(a, b, c, 0, 0, 0);
}

#define GLDS16(src, dst) \
  __builtin_amdgcn_global_load_lds((const __attribute__((address_space(1))) void*)(src), \
                                   (__attribute__((address_space(3))) void*)(dst), 16, 0, 0)

// ---------------- merged prep kernel ----------------
__global__ __launch_bounds__(256) void prep_all(const float* __restrict__ x, u16* __restrict__ xb,
                                                const float* __restrict__ Wa, u16* __restrict__ Wab,
                                                const float* __restrict__ Wp, u16* __restrict__ Wpb) {
  __shared__ float tile[32][33];
  const int blk = blockIdx.x;
  if (blk < 2048) {
    int i = blk * 256 + threadIdx.x;
    const f32x4* ip = (const f32x4*)x;
    f32x4 a = ip[2 * i], b2 = ip[2 * i + 1];
    u16x8 r;
    #pragma unroll
    for (int j = 0; j < 4; ++j) { r[j] = f2b(a[j]); r[4 + j] = f2b(b2[j]); }
    ((u16x8*)xb)[i] = r;
    return;
  }
  const float* in; u16* out; int K, N, bx, by;
  if (blk < 5120) {
    int idx = blk - 2048; in = Wa; out = Wab; K = CDIM; N = 3 * CDIM;
    bx = idx % 96; by = idx / 96;
  } else {
    int idx = blk - 5120; in = Wp; out = Wpb; K = CDIM; N = CDIM;
    bx = idx & 31; by = idx >> 5;
  }
  int n0 = bx * 32, k0 = by * 32;
  int c = threadIdx.x & 31, r0 = threadIdx.x >> 5;
  #pragma unroll
  for (int i = 0; i < 4; ++i) {
    int r = r0 + i * 8;
    tile[r][c] = in[(size_t)(k0 + r) * N + n0 + c];
  }
  __syncthreads();
  #pragma unroll
  for (int i = 0; i < 4; ++i) {
    int r = r0 + i * 8;
    out[(size_t)(n0 + r) * K + k0 + c] = f2b(tile[c][r]);
  }
}

// ---------------- GEMM1: 128x192 tile, 8 waves, 2 blocks/CU ----------------
__global__ __launch_bounds__(512, 4) void gemm_qkv128(const u16* __restrict__ A,
                                                      const u16* __restrict__ Bt,
                                                      const float* __restrict__ bias,
                                                      u16* __restrict__ Qo, u16* __restrict__ Ko,
                                                      u16* __restrict__ Vto) {
  __shared__ __align__(16) u16 As[2][128 * 64];   // 32 KB
  __shared__ __align__(16) u16 Bs[2][192 * 64];   // 48 KB
  const int tid = threadIdx.x, w = tid >> 6, lane = tid & 63;
  const int g = lane >> 4, lr = lane & 15;
  const int wr = w >> 2, wc = w & 3;
  const int bid = blockIdx.x;
  const int swz = (bid & 7) * 64 + (bid >> 3);
  const int tm = (swz & 31) * 128, tn = (swz >> 5) * 192;

  f32x4 acc[4][3];
  #pragma unroll
  for (int mi = 0; mi < 4; ++mi)
    #pragma unroll
    for (int ni = 0; ni < 3; ++ni)
      acc[mi][ni] = (f32x4){0.f, 0.f, 0.f, 0.f};

  auto STAGE = [&](int d, int kt) {
    const int k0 = kt << 6;
    #pragma unroll
    for (int j = 0; j < 2; ++j) {
      int ci = j * 512 + tid, row = ci >> 3, c8 = ci & 7;
      GLDS16(A + (size_t)(tm + row) * CDIM + k0 + ((c8 ^ (row & 7)) << 3),
             &As[d][row * 64 + c8 * 8]);
    }
    #pragma unroll
    for (int j = 0; j < 3; ++j) {
      int ci = j * 512 + tid, row = ci >> 3, c8 = ci & 7;
      GLDS16(Bt + (size_t)(tn + row) * CDIM + k0 + ((c8 ^ (row & 7)) << 3),
             &Bs[d][row * 64 + c8 * 8]);
    }
  };

  STAGE(0, 0);
  asm volatile("s_waitcnt vmcnt(0)" ::: "memory");
  __builtin_amdgcn_s_barrier();

  const int x7 = lr & 7;
  for (int t = 0; t < 16; ++t) {
    const int cur = t & 1;
    if (t < 15) STAGE(cur ^ 1, t + 1);

    frag_ab af[4][2], bf[3][2];
    #pragma unroll
    for (int mi = 0; mi < 4; ++mi) {
      int row = wr * 64 + mi * 16 + lr;
      #pragma unroll
      for (int ks = 0; ks < 2; ++ks)
        af[mi][ks] = *(const frag_ab*)&As[cur][row * 64 + ((((ks << 2) | g) ^ x7) << 3)];
    }
    #pragma unroll
    for (int ni = 0; ni < 3; ++ni) {
      int row = wc * 48 + ni * 16 + lr;
      #pragma unroll
      for (int ks = 0; ks < 2; ++ks)
        bf[ni][ks] = *(const frag_ab*)&Bs[cur][row * 64 + ((((ks << 2) | g) ^ x7) << 3)];
    }
    __builtin_amdgcn_s_setprio(1);
    #pragma unroll
    for (int mi = 0; mi < 4; ++mi)
      #pragma unroll
      for (int ni = 0; ni < 3; ++ni)
        #pragma unroll
        for (int ks = 0; ks < 2; ++ks)
          acc[mi][ni] = mfma16(af[mi][ks], bf[ni][ks], acc[mi][ni]);
    __builtin_amdgcn_s_setprio(0);

    asm volatile("s_waitcnt vmcnt(0)" ::: "memory");
    __builtin_amdgcn_s_barrier();
  }

  #pragma unroll
  for (int ni = 0; ni < 3; ++ni) {
    int n = tn + wc * 48 + ni * 16 + lr;
    float bv = bias[n];
    int which = n >> 10, c = n & 1023, h = c >> 6, d = c & 63;
    #pragma unroll
    for (int mi = 0; mi < 4; ++mi) {
      if (which == 2) {
        int t0 = tm + wr * 64 + mi * 16 + g * 4;
        int bb = t0 >> 11, tt = t0 & (N_CTX - 1);
        u16x4 pk;
        #pragma unroll
        for (int r = 0; r < 4; ++r) pk[r] = f2b(acc[mi][ni][r] + bv);
        *(u16x4*)&Vto[((size_t)(bb * NH + h) * HD + d) * N_CTX + tt] = pk;
      } else {
        u16* dst = (which == 0) ? Qo : Ko;
        float scl = (which == 0) ? 0.180336881f : 1.0f;   // (1/8)*log2(e)
        #pragma unroll
        for (int r = 0; r < 4; ++r) {
          int m = tm + wr * 64 + mi * 16 + g * 4 + r;
          int bb = m >> 11, tt = m & (N_CTX - 1);
          dst[((size_t)(bb * NH + h) * N_CTX + tt) * HD + d] = f2b((acc[mi][ni][r] + bv) * scl);
        }
      }
    }
  }
}

// ---------------- GEMM2: 128x64 tile, 8 waves (4x2), 2 blocks/CU (fp32 out) --------------
__global__ __launch_bounds__(512, 4) void gemm_proj128(const u16* __restrict__ A,
                                                       const u16* __restrict__ Bt,
                                                       const float* __restrict__ bias,
                                                       float* __restrict__ out) {
  __shared__ __align__(16) u16 As[2][128 * 64];   // 32 KB
  __shared__ __align__(16) u16 Bs[2][64 * 64];    // 16 KB
  const int tid = threadIdx.x, w = tid >> 6, lane = tid & 63;
  const int g = lane >> 4, lr = lane & 15;
  const int wr = w >> 1, wc = w & 1;
  const int bid = blockIdx.x;
  const int swz = (bid & 7) * 64 + (bid >> 3);
  const int tm = (swz & 31) * 128, tn = (swz >> 5) * 64;

  f32x4 acc[2][2];
  #pragma unroll
  for (int mi = 0; mi < 2; ++mi)
    #pragma unroll
    for (int ni = 0; ni < 2; ++ni)
      acc[mi][ni] = (f32x4){0.f, 0.f, 0.f, 0.f};

  auto STAGE = [&](int d, int kt) {
    const int k0 = kt << 6;
    #pragma unroll
    for (int j = 0; j < 2; ++j) {
      int ci = j * 512 + tid, row = ci >> 3, c8 = ci & 7;
      GLDS16(A + (size_t)(tm + row) * CDIM + k0 + ((c8 ^ (row & 7)) << 3),
             &As[d][row * 64 + c8 * 8]);
    }
    {
      int row = tid >> 3, c8 = tid & 7;
      GLDS16(Bt + (size_t)(tn + row) * CDIM + k0 + ((c8 ^ (row & 7)) << 3),
             &Bs[d][row * 64 + c8 * 8]);
    }
  };

  STAGE(0, 0);
  asm volatile("s_waitcnt vmcnt(0)" ::: "memory");
  __builtin_amdgcn_s_barrier();

  const int x7 = lr & 7;
  for (int t = 0; t < 16; ++t) {
    const int cur = t & 1;
    if (t < 15) STAGE(cur ^ 1, t + 1);

    frag_ab af[2][2], bf[2][2];
    #pragma unroll
    for (int mi = 0; mi < 2; ++mi) {
      int row = wr * 32 + mi * 16 + lr;
      #pragma unroll
      for (int ks = 0; ks < 2; ++ks)
        af[mi][ks] = *(const frag_ab*)&As[cur][row * 64 + ((((ks << 2) | g) ^ x7) << 3)];
    }
    #pragma unroll
    for (int ni = 0; ni < 2; ++ni) {
      int row = wc * 32 + ni * 16 + lr;
      #pragma unroll
      for (int ks = 0; ks < 2; ++ks)
        bf[ni][ks] = *(const frag_ab*)&Bs[cur][row * 64 + ((((ks << 2) | g) ^ x7) << 3)];
    }
    __builtin_amdgcn_s_setprio(1);
    #pragma unroll
    for (int mi = 0; mi < 2; ++mi)
      #pragma unroll
      for (int ni = 0; ni < 2; ++ni)
        #pragma unroll
        for (int ks = 0; ks < 2; ++ks)
          acc[mi][ni] = mfma16(af[mi][ks], bf[ni][ks], acc[mi][ni]);
    __builtin_amdgcn_s_setprio(0);

    asm volatile("s_waitcnt vmcnt(0)" ::: "memory");
    __builtin_amdgcn_s_barrier();
  }

  #pragma unroll
  for (int ni = 0; ni < 2; ++ni) {
    int n = tn + wc * 32 + ni * 16 + lr;
    float bv = bias[n];
    #pragma unroll
    for (int mi = 0; mi < 2; ++mi)
      #pragma unroll
      for (int r = 0; r < 4; ++r) {
        int m = tm + wr * 32 + mi * 16 + g * 4 + r;
        out[(size_t)m * CDIM + n] = acc[mi][ni][r] + bv;
      }
  }
}

// ---------------- flash attention (causal), split-K balanced, no-max exp2 softmax --------
// No-max softmax => O and ls are pure sums => split-K is EXACT: wave (grp,wq) processes
// k-tiles of parity grp for BOTH subtiles {qta=p, qtb=31-p}; one kf/vf load per k-tile
// feeds both. Every wave does ~17 tiles -> uniform load (fixes R10's 25% wave idle).
// Cross-group partial O/ps combined via LDS scratch (reusing Ks/Vs after the loop).
__global__ __launch_bounds__(512, 4) void attn_fwd(const u16* __restrict__ Q, const u16* __restrict__ K,
                                                   const u16* __restrict__ Vt, u16* __restrict__ Y) {
  __shared__ __align__(16) u16 Ks[4][64 * 64];    // 32 KB
  __shared__ __align__(16) u16 Vs[4][64 * 64];    // 32 KB
  const int orig = blockIdx.x;
  const int swz = (orig & 7) * 64 + (orig >> 3);  // 512 blocks = 8 XCDs x 64
  const int bh = swz >> 4;
  const int p  = swz & 15;
  const int qta = p, qtb = 31 - p;
  const int tid = threadIdx.x, w = tid >> 6, lane = tid & 63;
  const int grp = w >> 2, wq = w & 3;             // grp = k-parity; wq = 16-row slice
  const int g = lane >> 4, lr = lane & 15;
  const size_t base = (size_t)bh * N_CTX * HD;
  const u16* Kbh = K + base;
  const u16* Vbh = Vt + base;

  const int c8 = tid & 7, srow = tid >> 3;
  const size_t kOff = (size_t)srow * HD + (size_t)((c8 ^ (srow & 7)) * 8);
  const size_t vOff = (size_t)srow * N_CTX + (size_t)((c8 ^ (srow & 7)) * 8);

  frag_ab qfA[2], qfB[2];
  {
    const u16* qa = Q + base + (size_t)(qta * 64 + wq * 16 + lr) * HD + g * 8;
    qfA[0] = *(const frag_ab*)qa;  qfA[1] = *(const frag_ab*)(qa + 32);
    const u16* qb = Q + base + (size_t)(qtb * 64 + wq * 16 + lr) * HD + g * 8;
    qfB[0] = *(const frag_ab*)qb;  qfB[1] = *(const frag_ab*)(qb + 32);
  }

  float psA = 0.f, psB = 0.f;
  f32x4 oA[4], oB[4];
  #pragma unroll
  for (int d = 0; d < 4; ++d) { oA[d] = (f32x4){0,0,0,0}; oB[d] = (f32x4){0,0,0,0}; }

  auto STAGE = [&](int b, int kt) {
    GLDS16(Kbh + (size_t)kt * 64 * HD + kOff, &Ks[b][(size_t)tid * 8]);
    GLDS16(Vbh + (size_t)kt * 64 + vOff,      &Vs[b][(size_t)tid * 8]);
  };

  const int npair = (qtb + 2) >> 1;
  STAGE(0, 0);
  STAGE(1, 1);
  asm volatile("s_waitcnt vmcnt(0)" ::: "memory");
  __builtin_amdgcn_s_barrier();

  const int qrow = wq * 16 + lr;
  for (int i = 0; i < npair; ++i) {
    const int t = 2 * i + grp;                    // this wave's k-tile (parity grp)
    const int bb = t & 3;
    const int t0 = 2 * i;
    if (i + 1 < npair) { STAGE((t0 + 2) & 3, t0 + 2); STAGE((t0 + 3) & 3, t0 + 3); }

    if (t <= qtb) {
      // K frags for this single k-tile (serves BOTH subtiles)
      frag_ab kf[4][2];
      #pragma unroll
      for (int nf = 0; nf < 4; ++nf)
        #pragma unroll
        for (int ks = 0; ks < 2; ++ks)
          kf[nf][ks] = *(const frag_ab*)&Ks[bb][(size_t)(nf * 16 + lr) * 64 +
                                               (size_t)((((ks << 2) | g) ^ (lr & 7)) * 8)];
      const bool actA = (t <= qta);
      // S^T for B (and A if active)
      f32x4 sB[4], sA[4];
      __builtin_amdgcn_s_setprio(1);
      #pragma unroll
      for (int j = 0; j < 4; ++j) {
        f32x4 a = (f32x4){0.f, 0.f, 0.f, 0.f};
        a = mfma16(kf[j][0], qfB[0], a);
        a = mfma16(kf[j][1], qfB[1], a);
        sB[j] = a;
      }
      if (actA) {
        #pragma unroll
        for (int j = 0; j < 4; ++j) {
          f32x4 a = (f32x4){0.f, 0.f, 0.f, 0.f};
          a = mfma16(kf[j][0], qfA[0], a);
          a = mfma16(kf[j][1], qfA[1], a);
          sA[j] = a;
        }
      }
      __builtin_amdgcn_s_setprio(0);
      // masks (only exact diagonal tiles)
      if (t == qtb) {
        #pragma unroll
        for (int nf = 0; nf < 4; ++nf)
          #pragma unroll
          for (int r = 0; r < 4; ++r)
            if (nf * 16 + g * 4 + r > qrow) sB[nf][r] = -1e30f;
      }
      if (t == qta) {
        #pragma unroll
        for (int nf = 0; nf < 4; ++nf)
          #pragma unroll
          for (int r = 0; r < 4; ++r)
            if (nf * 16 + g * 4 + r > qrow) sA[nf][r] = -1e30f;
      }
      // P = exp2(S); partial sums
      #pragma unroll
      for (int j = 0; j < 4; ++j)
        #pragma unroll
        for (int r = 0; r < 4; ++r)
          sB[j][r] = __builtin_amdgcn_exp2f(sB[j][r]);
      psB += ((sB[0][0]+sB[0][1])+(sB[0][2]+sB[0][3])) + ((sB[1][0]+sB[1][1])+(sB[1][2]+sB[1][3]))
           + ((sB[2][0]+sB[2][1])+(sB[2][2]+sB[2][3])) + ((sB[3][0]+sB[3][1])+(sB[3][2]+sB[3][3]));
      frag_ab paB[2];
      #pragma unroll
      for (int ks = 0; ks < 2; ++ks)
        #pragma unroll
        for (int j = 0; j < 4; ++j) {
          paB[ks][j]     = (short)f2b(sB[2 * ks][j]);
          paB[ks][4 + j] = (short)f2b(sB[2 * ks + 1][j]);
        }
      frag_ab paA[2];
      if (actA) {
        #pragma unroll
        for (int j = 0; j < 4; ++j)
          #pragma unroll
          for (int r = 0; r < 4; ++r)
            sA[j][r] = __builtin_amdgcn_exp2f(sA[j][r]);
        psA += ((sA[0][0]+sA[0][1])+(sA[0][2]+sA[0][3])) + ((sA[1][0]+sA[1][1])+(sA[1][2]+sA[1][3]))
             + ((sA[2][0]+sA[2][1])+(sA[2][2]+sA[2][3])) + ((sA[3][0]+sA[3][1])+(sA[3][2]+sA[3][3]));
        #pragma unroll
        for (int ks = 0; ks < 2; ++ks)
          #pragma unroll
          for (int j = 0; j < 4; ++j) {
            paA[ks][j]     = (short)f2b(sA[2 * ks][j]);
            paA[ks][4 + j] = (short)f2b(sA[2 * ks + 1][j]);
          }
      }
      // O += P @ V (one V tile; lazy per-d frags; feeds both subtiles)
      #pragma unroll
      for (int d = 0; d < 4; ++d) {
        const int row = (d * 16 + lr) * 64;
        frag_ab vf[2];
        #pragma unroll
        for (int ks = 0; ks < 2; ++ks) {
          u16x4 lo = *(const u16x4*)&Vs[bb][row + (((ks * 4 + (g >> 1)) ^ (lr & 7)) * 8) + (g & 1) * 4];
          u16x4 hi = *(const u16x4*)&Vs[bb][row + (((ks * 4 + 2 + (g >> 1)) ^ (lr & 7)) * 8) + (g & 1) * 4];
          #pragma unroll
          for (int j = 0; j < 4; ++j) { vf[ks][j] = (short)lo[j]; vf[ks][4 + j] = (short)hi[j]; }
        }
        __builtin_amdgcn_s_setprio(1);
        oB[d] = mfma16(paB[0], vf[0], oB[d]);
        oB[d] = mfma16(paB[1], vf[1], oB[d]);
        if (actA) {
          oA[d] = mfma16(paA[0], vf[0], oA[d]);
          oA[d] = mfma16(paA[1], vf[1], oA[d]);
        }
        __builtin_amdgcn_s_setprio(0);
      }
    }

    asm volatile("s_waitcnt vmcnt(0)" ::: "memory");
    __builtin_amdgcn_s_barrier();
  }

  // ---- epilogue: cross-group combine via LDS scratch, then O/ls -> Y ----
  psA += __shfl_xor(psA, 16, 64);  psA += __shfl_xor(psA, 32, 64);
  psB += __shfl_xor(psB, 16, 64);  psB += __shfl_xor(psB, 32, 64);

  float* SA  = (float*)&Ks[0][0];       // 16 KB: subtile-A partials (written by grp1)
  float* SB  = (float*)&Vs[0][0];       // 16 KB: subtile-B partials (written by grp0)
  float* PSA = (float*)&Ks[2][0];       // 64 floats
  float* PSB = PSA + 64;

  if (grp == 1) {
    #pragma unroll
    for (int d = 0; d < 4; ++d)
      #pragma unroll
      for (int r = 0; r < 4; ++r)
        SA[(wq * 16 + g * 4 + r) * 64 + d * 16 + lr] = oA[d][r];
    if (g == 0) PSA[wq * 16 + lr] = psA;
  } else {
    #pragma unroll
    for (int d = 0; d < 4; ++d)
      #pragma unroll
      for (int r = 0; r < 4; ++r)
        SB[(wq * 16 + g * 4 + r) * 64 + d * 16 + lr] = oB[d][r];
    if (g == 0) PSB[wq * 16 + lr] = psB;
  }
  __syncthreads();

  const int b = bh >> 4, h = bh & 15;
  if (grp == 0) {
    float li = 1.0f / (psA + PSA[wq * 16 + lr]);
    #pragma unroll
    for (int r = 0; r < 4; ++r) {
      int src = (lane & 48) | (((lane >> 4) & 3) * 4 + r);
      float lir = __shfl(li, src, 64);
      int row = qta * 64 + wq * 16 + g * 4 + r;
      #pragma unroll
      for (int d = 0; d < 4; ++d) {
        float val = (oA[d][r] + SA[(wq * 16 + g * 4 + r) * 64 + d * 16 + lr]) * lir;
        Y[((size_t)(b * N_CTX + row)) * CDIM + h * HD + d * 16 + lr] = f2b(val);
      }
    }
  } else {
    float li = 1.0f / (psB + PSB[wq * 16 + lr]);
    #pragma unroll
    for (int r = 0; r < 4; ++r) {
      int src = (lane & 48) | (((lane >> 4) & 3) * 4 + r);
      float lir = __shfl(li, src, 64);
      int row = qtb * 64 + wq * 16 + g * 4 + r;
      #pragma unroll
      for (int d = 0; d < 4; ++d) {
        float val = (oB[d][r] + SB[(wq * 16 + g * 4 + r) * 64 + d * 16 + lr]) * lir;
        Y[((size_t)(b * N_CTX + row)) * CDIM + h * HD + d * 16 + lr] = f2b(val);
      }
    }
  }
}

// ---------------- launch ----------------
extern "C" void kernel_launch(void* const* d_in, const int* in_sizes, int n_in,
                              void* d_out, int out_size, void* d_ws, size_t ws_size,
                              hipStream_t stream) {
  const float* x      = (const float*)d_in[0];
  const float* W_attn = (const float*)d_in[1];
  const float* b_attn = (const float*)d_in[2];
  const float* W_proj = (const float*)d_in[3];
  const float* b_proj = (const float*)d_in[4];
  float* out = (float*)d_out;
  char* ws = (char*)d_ws;

  u16* xb  = (u16*)(ws);                       // 8 MB  (reused for y)
  u16* Wab = (u16*)(ws + ((size_t)8 << 20));   // 6 MB  W_attn^T bf16
  u16* Wpb = (u16*)(ws + ((size_t)14 << 20));  // 2 MB  W_proj^T bf16
  u16* Qb  = (u16*)(ws + ((size_t)16 << 20));  // 8 MB  (pre-scaled)
  u16* Kb  = (u16*)(ws + ((size_t)24 << 20));  // 8 MB
  u16* Vtb = (u16*)(ws + ((size_t)32 << 20));  // 8 MB  V^T
  u16* yb  = xb;

  prep_all<<<6144, 256, 0, stream>>>(x, xb, W_attn, Wab, W_proj, Wpb);
  gemm_qkv128<<<512, 512, 0, stream>>>(xb, Wab, b_attn, Qb, Kb, Vtb);
  attn_fwd<<<512, 512, 0, stream>>>(Qb, Kb, Vtb, yb);
  gemm_proj128<<<512, 512, 0, stream>>>(yb, Wpb, b_proj, out);
}

// Round 12
// 89.409 us; speedup vs baseline: 1.2200x; 1.2200x over previous
//
#include <hip/hip_runtime.h>
#include <hip/hip_bf16.h>

typedef unsigned short u16;
using frag_ab = __attribute__((ext_vector_type(8))) short;
using f32x4   = __attribute__((ext_vector_type(4))) float;
using u16x4   = __attribute__((ext_vector_type(4))) unsigned short;
using u16x8   = __attribute__((ext_vector_type(8))) unsigned short;

#define N_CTX   2048
#define NBATCH  2
#define CDIM    1024
#define NH      16
#define HD      64

__device__ __forceinline__ u16 f2b(float f) {
  __hip_bfloat16 h = __float2bfloat16(f);
  return __builtin_bit_cast(u16, h);
}

__device__ __forceinline__ f32x4 mfma16(frag_ab a, frag_ab b, f32x4 c) {
  return __builtin_amdgcn_mfma_f32_16x16x32_bf16(a, b, c, 0, 0, 0);
}

#define GLDS16(src, dst) \
  __builtin_amdgcn_global_load_lds((const __attribute__((address_space(1))) void*)(src), \
                                   (__attribute__((address_space(3))) void*)(dst), 16, 0, 0)

// ---------------- merged prep kernel ----------------
__global__ __launch_bounds__(256) void prep_all(const float* __restrict__ x, u16* __restrict__ xb,
                                                const float* __restrict__ Wa, u16* __restrict__ Wab,
                                                const float* __restrict__ Wp, u16* __restrict__ Wpb) {
  __shared__ float tile[32][33];
  const int blk = blockIdx.x;
  if (blk < 2048) {
    int i = blk * 256 + threadIdx.x;
    const f32x4* ip = (const f32x4*)x;
    f32x4 a = ip[2 * i], b2 = ip[2 * i + 1];
    u16x8 r;
    #pragma unroll
    for (int j = 0; j < 4; ++j) { r[j] = f2b(a[j]); r[4 + j] = f2b(b2[j]); }
    ((u16x8*)xb)[i] = r;
    return;
  }
  const float* in; u16* out; int K, N, bx, by;
  if (blk < 5120) {
    int idx = blk - 2048; in = Wa; out = Wab; K = CDIM; N = 3 * CDIM;
    bx = idx % 96; by = idx / 96;
  } else {
    int idx = blk - 5120; in = Wp; out = Wpb; K = CDIM; N = CDIM;
    bx = idx & 31; by = idx >> 5;
  }
  int n0 = bx * 32, k0 = by * 32;
  int c = threadIdx.x & 31, r0 = threadIdx.x >> 5;
  #pragma unroll
  for (int i = 0; i < 4; ++i) {
    int r = r0 + i * 8;
    tile[r][c] = in[(size_t)(k0 + r) * N + n0 + c];
  }
  __syncthreads();
  #pragma unroll
  for (int i = 0; i < 4; ++i) {
    int r = r0 + i * 8;
    out[(size_t)(n0 + r) * K + k0 + c] = f2b(tile[c][r]);
  }
}

// ---------------- GEMM1: 128x192 tile, 8 waves, 2 blocks/CU ----------------
__global__ __launch_bounds__(512, 4) void gemm_qkv128(const u16* __restrict__ A,
                                                      const u16* __restrict__ Bt,
                                                      const float* __restrict__ bias,
                                                      u16* __restrict__ Qo, u16* __restrict__ Ko,
                                                      u16* __restrict__ Vto) {
  __shared__ __align__(16) u16 As[2][128 * 64];   // 32 KB
  __shared__ __align__(16) u16 Bs[2][192 * 64];   // 48 KB
  const int tid = threadIdx.x, w = tid >> 6, lane = tid & 63;
  const int g = lane >> 4, lr = lane & 15;
  const int wr = w >> 2, wc = w & 3;
  const int bid = blockIdx.x;
  const int swz = (bid & 7) * 64 + (bid >> 3);
  const int tm = (swz & 31) * 128, tn = (swz >> 5) * 192;

  f32x4 acc[4][3];
  #pragma unroll
  for (int mi = 0; mi < 4; ++mi)
    #pragma unroll
    for (int ni = 0; ni < 3; ++ni)
      acc[mi][ni] = (f32x4){0.f, 0.f, 0.f, 0.f};

  auto STAGE = [&](int d, int kt) {
    const int k0 = kt << 6;
    #pragma unroll
    for (int j = 0; j < 2; ++j) {
      int ci = j * 512 + tid, row = ci >> 3, c8 = ci & 7;
      GLDS16(A + (size_t)(tm + row) * CDIM + k0 + ((c8 ^ (row & 7)) << 3),
             &As[d][row * 64 + c8 * 8]);
    }
    #pragma unroll
    for (int j = 0; j < 3; ++j) {
      int ci = j * 512 + tid, row = ci >> 3, c8 = ci & 7;
      GLDS16(Bt + (size_t)(tn + row) * CDIM + k0 + ((c8 ^ (row & 7)) << 3),
             &Bs[d][row * 64 + c8 * 8]);
    }
  };

  STAGE(0, 0);
  asm volatile("s_waitcnt vmcnt(0)" ::: "memory");
  __builtin_amdgcn_s_barrier();

  const int x7 = lr & 7;
  for (int t = 0; t < 16; ++t) {
    const int cur = t & 1;
    if (t < 15) STAGE(cur ^ 1, t + 1);

    frag_ab af[4][2], bf[3][2];
    #pragma unroll
    for (int mi = 0; mi < 4; ++mi) {
      int row = wr * 64 + mi * 16 + lr;
      #pragma unroll
      for (int ks = 0; ks < 2; ++ks)
        af[mi][ks] = *(const frag_ab*)&As[cur][row * 64 + ((((ks << 2) | g) ^ x7) << 3)];
    }
    #pragma unroll
    for (int ni = 0; ni < 3; ++ni) {
      int row = wc * 48 + ni * 16 + lr;
      #pragma unroll
      for (int ks = 0; ks < 2; ++ks)
        bf[ni][ks] = *(const frag_ab*)&Bs[cur][row * 64 + ((((ks << 2) | g) ^ x7) << 3)];
    }
    __builtin_amdgcn_s_setprio(1);
    #pragma unroll
    for (int mi = 0; mi < 4; ++mi)
      #pragma unroll
      for (int ni = 0; ni < 3; ++ni)
        #pragma unroll
        for (int ks = 0; ks < 2; ++ks)
          acc[mi][ni] = mfma16(af[mi][ks], bf[ni][ks], acc[mi][ni]);
    __builtin_amdgcn_s_setprio(0);

    asm volatile("s_waitcnt vmcnt(0)" ::: "memory");
    __builtin_amdgcn_s_barrier();
  }

  #pragma unroll
  for (int ni = 0; ni < 3; ++ni) {
    int n = tn + wc * 48 + ni * 16 + lr;
    float bv = bias[n];
    int which = n >> 10, c = n & 1023, h = c >> 6, d = c & 63;
    #pragma unroll
    for (int mi = 0; mi < 4; ++mi) {
      if (which == 2) {
        int t0 = tm + wr * 64 + mi * 16 + g * 4;
        int bb = t0 >> 11, tt = t0 & (N_CTX - 1);
        u16x4 pk;
        #pragma unroll
        for (int r = 0; r < 4; ++r) pk[r] = f2b(acc[mi][ni][r] + bv);
        *(u16x4*)&Vto[((size_t)(bb * NH + h) * HD + d) * N_CTX + tt] = pk;
      } else {
        u16* dst = (which == 0) ? Qo : Ko;
        float scl = (which == 0) ? 0.180336881f : 1.0f;   // (1/8)*log2(e)
        #pragma unroll
        for (int r = 0; r < 4; ++r) {
          int m = tm + wr * 64 + mi * 16 + g * 4 + r;
          int bb = m >> 11, tt = m & (N_CTX - 1);
          dst[((size_t)(bb * NH + h) * N_CTX + tt) * HD + d] = f2b((acc[mi][ni][r] + bv) * scl);
        }
      }
    }
  }
}

// ---------------- GEMM2: 128x64 tile, 8 waves (4x2), 2 blocks/CU (fp32 out) --------------
__global__ __launch_bounds__(512, 4) void gemm_proj128(const u16* __restrict__ A,
                                                       const u16* __restrict__ Bt,
                                                       const float* __restrict__ bias,
                                                       float* __restrict__ out) {
  __shared__ __align__(16) u16 As[2][128 * 64];   // 32 KB
  __shared__ __align__(16) u16 Bs[2][64 * 64];    // 16 KB
  const int tid = threadIdx.x, w = tid >> 6, lane = tid & 63;
  const int g = lane >> 4, lr = lane & 15;
  const int wr = w >> 1, wc = w & 1;
  const int bid = blockIdx.x;
  const int swz = (bid & 7) * 64 + (bid >> 3);
  const int tm = (swz & 31) * 128, tn = (swz >> 5) * 64;

  f32x4 acc[2][2];
  #pragma unroll
  for (int mi = 0; mi < 2; ++mi)
    #pragma unroll
    for (int ni = 0; ni < 2; ++ni)
      acc[mi][ni] = (f32x4){0.f, 0.f, 0.f, 0.f};

  auto STAGE = [&](int d, int kt) {
    const int k0 = kt << 6;
    #pragma unroll
    for (int j = 0; j < 2; ++j) {
      int ci = j * 512 + tid, row = ci >> 3, c8 = ci & 7;
      GLDS16(A + (size_t)(tm + row) * CDIM + k0 + ((c8 ^ (row & 7)) << 3),
             &As[d][row * 64 + c8 * 8]);
    }
    {
      int row = tid >> 3, c8 = tid & 7;
      GLDS16(Bt + (size_t)(tn + row) * CDIM + k0 + ((c8 ^ (row & 7)) << 3),
             &Bs[d][row * 64 + c8 * 8]);
    }
  };

  STAGE(0, 0);
  asm volatile("s_waitcnt vmcnt(0)" ::: "memory");
  __builtin_amdgcn_s_barrier();

  const int x7 = lr & 7;
  for (int t = 0; t < 16; ++t) {
    const int cur = t & 1;
    if (t < 15) STAGE(cur ^ 1, t + 1);

    frag_ab af[2][2], bf[2][2];
    #pragma unroll
    for (int mi = 0; mi < 2; ++mi) {
      int row = wr * 32 + mi * 16 + lr;
      #pragma unroll
      for (int ks = 0; ks < 2; ++ks)
        af[mi][ks] = *(const frag_ab*)&As[cur][row * 64 + ((((ks << 2) | g) ^ x7) << 3)];
    }
    #pragma unroll
    for (int ni = 0; ni < 2; ++ni) {
      int row = wc * 32 + ni * 16 + lr;
      #pragma unroll
      for (int ks = 0; ks < 2; ++ks)
        bf[ni][ks] = *(const frag_ab*)&Bs[cur][row * 64 + ((((ks << 2) | g) ^ x7) << 3)];
    }
    __builtin_amdgcn_s_setprio(1);
    #pragma unroll
    for (int mi = 0; mi < 2; ++mi)
      #pragma unroll
      for (int ni = 0; ni < 2; ++ni)
        #pragma unroll
        for (int ks = 0; ks < 2; ++ks)
          acc[mi][ni] = mfma16(af[mi][ks], bf[ni][ks], acc[mi][ni]);
    __builtin_amdgcn_s_setprio(0);

    asm volatile("s_waitcnt vmcnt(0)" ::: "memory");
    __builtin_amdgcn_s_barrier();
  }

  #pragma unroll
  for (int ni = 0; ni < 2; ++ni) {
    int n = tn + wc * 32 + ni * 16 + lr;
    float bv = bias[n];
    #pragma unroll
    for (int mi = 0; mi < 2; ++mi)
      #pragma unroll
      for (int r = 0; r < 4; ++r) {
        int m = tm + wr * 32 + mi * 16 + g * 4 + r;
        out[(size_t)m * CDIM + n] = acc[mi][ni][r] + bv;
      }
  }
}

// ---------------- flash attention (causal): one q-tile/block, split-K parity waves -------
// No-max exp2 softmax => O/ls are pure sums => k-split is exact. Block = (bh, qt);
// 8 waves = 4 row-slices x 2 k-parities; wave (grp,wq) does k-tiles t=2i+grp of its
// OWN q-tile only -> single accumulator set per wave (no R11 spill), wave idle ~3%.
// qt-descending dispatch + XCD swizzle (4 bh/XCD). Cross-parity combine via LDS.
__global__ __launch_bounds__(512, 4) void attn_fwd(const u16* __restrict__ Q, const u16* __restrict__ K,
                                                   const u16* __restrict__ Vt, u16* __restrict__ Y) {
  __shared__ __align__(16) u16 Ks[4][64 * 64];    // 32 KB (reused as f32 scratch in epilogue)
  __shared__ __align__(16) u16 Vs[4][64 * 64];    // 32 KB
  const int orig = blockIdx.x;                    // 1024 blocks
  const int bh = (orig & 7) * 4 + ((orig >> 3) & 3);   // 4 bh per XCD
  const int qt = 31 - (orig >> 5);                     // heavy blocks dispatch first
  const int tid = threadIdx.x, w = tid >> 6, lane = tid & 63;
  const int grp = w >> 2, wq = w & 3;             // grp = k-parity, wq = 16-row slice
  const int g = lane >> 4, lr = lane & 15;
  const size_t base = (size_t)bh * N_CTX * HD;
  const u16* Kbh = K + base;
  const u16* Vbh = Vt + base;

  const int c8 = tid & 7, srow = tid >> 3;
  const size_t kOff = (size_t)srow * HD + (size_t)((c8 ^ (srow & 7)) * 8);
  const size_t vOff = (size_t)srow * N_CTX + (size_t)((c8 ^ (srow & 7)) * 8);

  frag_ab qf[2];
  {
    const u16* qp = Q + base + (size_t)(qt * 64 + wq * 16 + lr) * HD + g * 8;
    qf[0] = *(const frag_ab*)qp;  qf[1] = *(const frag_ab*)(qp + 32);
  }

  float ps = 0.f;
  f32x4 o[4];
  #pragma unroll
  for (int d = 0; d < 4; ++d) o[d] = (f32x4){0.f, 0.f, 0.f, 0.f};

  auto STAGE = [&](int b, int kt) {
    GLDS16(Kbh + (size_t)kt * 64 * HD + kOff, &Ks[b][(size_t)tid * 8]);
    GLDS16(Vbh + (size_t)kt * 64 + vOff,      &Vs[b][(size_t)tid * 8]);
  };

  const int niter = (qt + 2) >> 1;
  STAGE(0, 0);
  STAGE(1, 1);                                    // kt=1 always within buffer
  asm volatile("s_waitcnt vmcnt(0)" ::: "memory");
  __builtin_amdgcn_s_barrier();

  const int qrow = wq * 16 + lr;
  for (int i = 0; i < niter; ++i) {
    const int t0 = 2 * i;
    const int t  = t0 + grp;                      // this wave's k-tile
    if (i + 1 < niter) { STAGE((t0 + 2) & 3, t0 + 2); STAGE((t0 + 3) & 3, t0 + 3); }

    if (t <= qt) {
      const int bb = t & 3;
      frag_ab kf[4][2];
      #pragma unroll
      for (int nf = 0; nf < 4; ++nf)
        #pragma unroll
        for (int ks = 0; ks < 2; ++ks)
          kf[nf][ks] = *(const frag_ab*)&Ks[bb][(size_t)(nf * 16 + lr) * 64 +
                                                (size_t)((((ks << 2) | g) ^ (lr & 7)) * 8)];
      f32x4 s[4];
      __builtin_amdgcn_s_setprio(1);
      #pragma unroll
      for (int j = 0; j < 4; ++j) {
        f32x4 a = (f32x4){0.f, 0.f, 0.f, 0.f};
        a = mfma16(kf[j][0], qf[0], a);
        a = mfma16(kf[j][1], qf[1], a);
        s[j] = a;
      }
      __builtin_amdgcn_s_setprio(0);
      if (t == qt) {                              // diagonal mask
        #pragma unroll
        for (int nf = 0; nf < 4; ++nf)
          #pragma unroll
          for (int r = 0; r < 4; ++r)
            if (nf * 16 + g * 4 + r > qrow) s[nf][r] = -1e30f;
      }
      #pragma unroll
      for (int j = 0; j < 4; ++j)
        #pragma unroll
        for (int r = 0; r < 4; ++r)
          s[j][r] = __builtin_amdgcn_exp2f(s[j][r]);
      ps += ((s[0][0]+s[0][1])+(s[0][2]+s[0][3])) + ((s[1][0]+s[1][1])+(s[1][2]+s[1][3]))
          + ((s[2][0]+s[2][1])+(s[2][2]+s[2][3])) + ((s[3][0]+s[3][1])+(s[3][2]+s[3][3]));
      frag_ab pa[2];
      #pragma unroll
      for (int ks = 0; ks < 2; ++ks)
        #pragma unroll
        for (int j = 0; j < 4; ++j) {
          pa[ks][j]     = (short)f2b(s[2 * ks][j]);
          pa[ks][4 + j] = (short)f2b(s[2 * ks + 1][j]);
        }
      #pragma unroll
      for (int d = 0; d < 4; ++d) {
        const int row = (d * 16 + lr) * 64;
        frag_ab vf[2];
        #pragma unroll
        for (int ks = 0; ks < 2; ++ks) {
          u16x4 lo = *(const u16x4*)&Vs[bb][row + (((ks * 4 + (g >> 1)) ^ (lr & 7)) * 8) + (g & 1) * 4];
          u16x4 hi = *(const u16x4*)&Vs[bb][row + (((ks * 4 + 2 + (g >> 1)) ^ (lr & 7)) * 8) + (g & 1) * 4];
          #pragma unroll
          for (int j = 0; j < 4; ++j) { vf[ks][j] = (short)lo[j]; vf[ks][4 + j] = (short)hi[j]; }
        }
        __builtin_amdgcn_s_setprio(1);
        o[d] = mfma16(pa[0], vf[0], o[d]);
        o[d] = mfma16(pa[1], vf[1], o[d]);
        __builtin_amdgcn_s_setprio(0);
      }
    }

    asm volatile("s_waitcnt vmcnt(0)" ::: "memory");
    __builtin_amdgcn_s_barrier();
  }

  // ---- epilogue: cross-parity combine via LDS, then O/ls -> Y ----
  ps += __shfl_xor(ps, 16, 64);
  ps += __shfl_xor(ps, 32, 64);

  float* SO = (float*)&Ks[0][0];        // 16 KB: grp1 partial O (64 rows x 64 cols)
  float* PS = (float*)&Vs[0][0];        // 64 floats: grp1 partial ps

  if (grp == 1) {
    #pragma unroll
    for (int d = 0; d < 4; ++d)
      #pragma unroll
      for (int r = 0; r < 4; ++r)
        SO[(wq * 16 + g * 4 + r) * 64 + d * 16 + lr] = o[d][r];
    if (g == 0) PS[wq * 16 + lr] = ps;
  }
  __syncthreads();

  if (grp == 0) {
    const int b = bh >> 4, h = bh & 15;
    float li = 1.0f / (ps + PS[wq * 16 + lr]);
    #pragma unroll
    for (int r = 0; r < 4; ++r) {
      int src = (lane & 48) | (((lane >> 4) & 3) * 4 + r);
      float lir = __shfl(li, src, 64);
      int row = qt * 64 + wq * 16 + g * 4 + r;
      #pragma unroll
      for (int d = 0; d < 4; ++d) {
        float val = (o[d][r] + SO[(wq * 16 + g * 4 + r) * 64 + d * 16 + lr]) * lir;
        Y[((size_t)(b * N_CTX + row)) * CDIM + h * HD + d * 16 + lr] = f2b(val);
      }
    }
  }
}

// ---------------- launch ----------------
extern "C" void kernel_launch(void* const* d_in, const int* in_sizes, int n_in,
                              void* d_out, int out_size, void* d_ws, size_t ws_size,
                              hipStream_t stream) {
  const float* x      = (const float*)d_in[0];
  const float* W_attn = (const float*)d_in[1];
  const float* b_attn = (const float*)d_in[2];
  const float* W_proj = (const float*)d_in[3];
  const float* b_proj = (const float*)d_in[4];
  float* out = (float*)d_out;
  char* ws = (char*)d_ws;

  u16* xb  = (u16*)(ws);                       // 8 MB  (reused for y)
  u16* Wab = (u16*)(ws + ((size_t)8 << 20));   // 6 MB  W_attn^T bf16
  u16* Wpb = (u16*)(ws + ((size_t)14 << 20));  // 2 MB  W_proj^T bf16
  u16* Qb  = (u16*)(ws + ((size_t)16 << 20));  // 8 MB  (pre-scaled)
  u16* Kb  = (u16*)(ws + ((size_t)24 << 20));  // 8 MB
  u16* Vtb = (u16*)(ws + ((size_t)32 << 20));  // 8 MB  V^T
  u16* yb  = xb;

  prep_all<<<6144, 256, 0, stream>>>(x, xb, W_attn, Wab, W_proj, Wpb);
  gemm_qkv128<<<512, 512, 0, stream>>>(xb, Wab, b_attn, Qb, Kb, Vtb);
  attn_fwd<<<1024, 512, 0, stream>>>(Qb, Kb, Vtb, yb);
  gemm_proj128<<<512, 512, 0, stream>>>(yb, Wpb, b_proj, out);
}